// Round 17
// baseline (97.101 us; speedup 1.0000x reference)
//
#include <hip/hip_runtime.h>
#include <hip/hip_bf16.h>

// ---------------------------------------------------------------------------
// Def_DownSampling, round 17.
//  * gaus_w identical per (oc,ic) => gaussian path uses channel-summed field.
//  * conv3+avgpool folded to stride-2 4^3 conv (W4), exact algebra.
//  * D via bf16 MFMA; Dsum kept fp32 (packed dot) for the grid path.
//  * R17: conv barriers halved (32 -> 16): ic-PAIR double buffering for
//    taps (tilepair[2][2x1296]) and weights; wsl replaced by per-pair
//    staged wsb (LDS 38.4 KB, still 4 blocks/CU). Loads get a full
//    2-COMPT window; unroll-2 avoids register copies. Values bit-identical.
// Outputs: y (2,32,32,32,32) | D (2,32,32,32,32) | grid-mean (2,32,32,32,3)
// ---------------------------------------------------------------------------

#define XN 64
#define DN 32
#define C  32
#define XVOL (XN * XN * XN)   // 262144
#define DVOL (DN * DN * DN)   // 32768

typedef __attribute__((ext_vector_type(8))) short short8v;
typedef __attribute__((ext_vector_type(4))) float float4v;

struct __attribute__((packed, aligned(4))) f4u { float4v v; };
struct __attribute__((packed, aligned(4))) s8u { short8v v; };

static __device__ __forceinline__ short f2bf(float f) {
    union { float f; unsigned u; } v; v.f = f;
    unsigned r = (v.u + 0x7fffu + ((v.u >> 16) & 1u)) >> 16;   // RNE
    return (short)r;
}

static __device__ __forceinline__ unsigned pk2(float a, float b) {
    __hip_bfloat162 h = __float22bfloat162_rn(float2{a, b});
    union { __hip_bfloat162 h2; unsigned u; } cv; cv.h2 = h;
    return cv.u;
}

// W4[ic][u][oc] = (1/8) sum_{s in {0,1}^3} conv_w[oc][ic][u-s]
static __device__ __forceinline__ float w4val(const float* __restrict__ conv_w,
                                              int ic, int u, int oc) {
    int uz = u >> 4, uy = (u >> 2) & 3, ux = u & 3;
    float s = 0.f;
    #pragma unroll
    for (int sz = 0; sz < 2; ++sz) {
        int tz = uz - sz; if (tz < 0 || tz > 2) continue;
        #pragma unroll
        for (int sy = 0; sy < 2; ++sy) {
            int ty = uy - sy; if (ty < 0 || ty > 2) continue;
            #pragma unroll
            for (int sx = 0; sx < 2; ++sx) {
                int tx = ux - sx; if (tx < 0 || tx > 2) continue;
                s += conv_w[(oc * C + ic) * 27 + tz * 9 + ty * 3 + tx];
            }
        }
    }
    return 0.125f * s;
}

// ---- K0: blocks 0..255 pack A-fragments (bf16) + biassum;
//          blocks 256..511 compute wsum[k] = sum_oc W4[k][oc] via shfl tree.
__global__ __launch_bounds__(256) void k_prep(const float* __restrict__ conv_w,
                                              const float* __restrict__ conv_b,
                                              unsigned short* __restrict__ wfrag,
                                              float* __restrict__ wsum) {
    int bid = blockIdx.x;
    int tid = threadIdx.x;
    if (bid < 256) {
        int i = bid * 256 + tid;                // 65536
        int e = i & 7;
        int l = (i >> 3) & 63;
        int sf = i >> 9;
        int f = sf & 1, step = sf >> 1;
        int oc = f * 16 + (l & 15);
        int k = step * 32 + ((l >> 4) * 8 + e);
        float v = w4val(conv_w, k >> 6, k & 63, oc);
        wfrag[i] = (unsigned short)f2bf(v);
        if (i == 0) {
            float s = 0.f;
            for (int o = 0; o < C; ++o) s += conv_b[o];
            wsum[2048] = s;
        }
    } else {
        int i2 = (bid - 256) * 256 + tid;       // 65536 = 2048 k x 32 oc
        int oc = tid & 31;
        int kk = i2 >> 5;
        float v = w4val(conv_w, kk >> 6, kk & 63, oc);
        v += __shfl_xor(v, 1, 64);
        v += __shfl_xor(v, 2, 64);
        v += __shfl_xor(v, 4, 64);
        v += __shfl_xor(v, 8, 64);
        v += __shfl_xor(v, 16, 64);
        if (oc == 0) wsum[kk] = v;
    }
}

// ---- K1: MFMA conv. 1024 blocks x 256 thr (4 waves).
// Wave w = output (zt*2+(w>>1), yt*2+(w&1), xt*16 + col), all 32 oc.
// Pair-granular double buffers: taps tilepair[2][2x1296] fp32 (zero-padded),
// weights wbuf[2] (2 ic each), wsum slice wsb[2][132]. 16 barriers total.
#define NSTG (6 * 6 * 34)     // 1224 staged floats per ic
#define TILEF (6 * 6 * 36)    // 1296 with row padding

__global__ __launch_bounds__(256) void k_conv_mfma(
        const float* __restrict__ x, const unsigned short* __restrict__ wfrag,
        const float* __restrict__ wsum, const float* __restrict__ bias,
        float* __restrict__ Dout, float* __restrict__ Dsum) {
    __shared__ float tilepair[2][2 * TILEF];
    __shared__ char wbuf[2 * 8320];
    __shared__ float wsb[2][132];
    int tid = threadIdx.x;

    int bid = blockIdx.x;
    int wid = (bid & 7) * 128 + (bid >> 3);      // XCD-chunked swizzle (1024%8==0)
    int xt = wid & 1;
    int yt = (wid >> 1) & 15;
    int zt = (wid >> 5) & 15;
    int b  = wid >> 9;
    int w = tid >> 6, lane = tid & 63;
    int col = lane & 15, g = lane >> 4;
    int wpz = w >> 1, wpy = w & 1;
    int pz = zt * 2 + wpz, py = yt * 2 + wpy, px = xt * 16 + col;

    const float* xb = x + (size_t)b * C * XVOL;
    const char* wfb = (const char*)wfrag;
    int wsdst = (tid >> 6) * 1040 + (tid & 63) * 16;

    // hoisted tap-staging index math (ic-invariant): i = tid + it*256 < 1224
    int gz0 = zt * 4 - 1, gy0 = yt * 4 - 1, gx0 = xt * 32 - 1;
    int  soff[5], sdst[5];
    bool sval[5], swr[5];
    #pragma unroll
    for (int it = 0; it < 5; ++it) {
        int i = tid + it * 256;
        int lx = i % 34; int r = i / 34; int ly = r % 6; int lz = r / 6;
        int gz = gz0 + lz, gy = gy0 + ly, gx = gx0 + lx;
        bool inr = i < NSTG;
        swr[it]  = inr;
        sval[it] = inr && (unsigned)gz < XN && (unsigned)gy < XN && (unsigned)gx < XN;
        soff[it] = ((gz & 63) * XN + (gy & 63)) * XN + (gx & 63);
        sdst[it] = inr ? (lz * 6 + ly) * 36 + lx : 0;
    }

    int base_g = ((2 * wpz + (g >> 1)) * 6 + 2 * wpy + (g & 1) * 2) * 36 + 2 * col;

    float4v acc0 = {0.f, 0.f, 0.f, 0.f};
    float4v acc1 = {0.f, 0.f, 0.f, 0.f};
    float4v dpv = {0.f, 0.f, 0.f, 0.f};
    float svA[10], svB[10];
    short8v sg0, sg1;
    float wv;

// load both ics of pair p into SV[10]
#define TLOADP(SV, p) do {                                                   \
    const float* xp0 = xb + (size_t)(2 * (p)) * XVOL;                        \
    _Pragma("unroll")                                                        \
    for (int it = 0; it < 5; ++it)                                           \
        SV[it] = sval[it] ? xp0[soff[it]] : 0.f;                             \
    const float* xp1 = xp0 + XVOL;                                           \
    _Pragma("unroll")                                                        \
    for (int it = 0; it < 5; ++it)                                           \
        SV[5 + it] = sval[it] ? xp1[soff[it]] : 0.f;                         \
} while (0)

#define TWRITEP(bf, SV) do {                                                 \
    float* d0 = tilepair[bf];                                                \
    _Pragma("unroll")                                                        \
    for (int it = 0; it < 5; ++it)                                           \
        if (swr[it]) d0[sdst[it]] = SV[it];                                  \
    float* d1 = tilepair[bf] + TILEF;                                        \
    _Pragma("unroll")                                                        \
    for (int it = 0; it < 5; ++it)                                           \
        if (swr[it]) d1[sdst[it]] = SV[5 + it];                              \
} while (0)

#define WLOAD(p) do {                                                        \
    const char* wp = wfb + (size_t)(p) * 8192 + tid * 16;                    \
    sg0 = ((const s8u*)(wp))->v;                                             \
    sg1 = ((const s8u*)(wp + 4096))->v;                                      \
    wv = (tid < 128) ? wsum[(p) * 128 + tid] : 0.f;                          \
} while (0)

#define WWRITE(bf) do {                                                      \
    *(short8v*)(wbuf + (bf) * 8320 + wsdst) = sg0;                           \
    *(short8v*)(wbuf + (bf) * 8320 + 4160 + wsdst) = sg1;                    \
    if (tid < 128) wsb[bf][tid] = wv;                                        \
} while (0)

// compute one ic; icL = ic&1 selects half of the pair buffers
#define COMPT(bf, icL) do {                                                  \
    const float* t = tilepair[bf] + (icL) * TILEF;                           \
    _Pragma("unroll")                                                        \
    for (int h5 = 0; h5 < 2; ++h5) {                                         \
        int off0 = base_g + h5 * 432;                                        \
        float2 v01 = *(const float2*)&t[off0];                               \
        float2 v23 = *(const float2*)&t[off0 + 2];                           \
        float2 v45 = *(const float2*)&t[off0 + 36];                          \
        float2 v67 = *(const float2*)&t[off0 + 38];                          \
        float4v r0 = {v01.x, v01.y, v23.x, v23.y};                           \
        float4v r1 = {v45.x, v45.y, v67.x, v67.y};                           \
        const float4v wlo = *(const float4v*)&wsb[bf][((icL) * 2 + h5) * 32 + g * 8];     \
        const float4v whi = *(const float4v*)&wsb[bf][((icL) * 2 + h5) * 32 + g * 8 + 4]; \
        dpv += wlo * r0;                                                     \
        dpv += whi * r1;                                                     \
        union { short8v s; unsigned u[4]; } Bv;                              \
        Bv.u[0] = pk2(r0[0], r0[1]); Bv.u[1] = pk2(r0[2], r0[3]);            \
        Bv.u[2] = pk2(r1[0], r1[1]); Bv.u[3] = pk2(r1[2], r1[3]);            \
        const char* wl = wbuf + (bf) * 8320 + (icL) * 4160 + lane * 16;      \
        short8v w0 = *(const short8v*)(wl + (h5 * 2) * 1040);                \
        short8v w1 = *(const short8v*)(wl + (h5 * 2 + 1) * 1040);            \
        acc0 = __builtin_amdgcn_mfma_f32_16x16x32_bf16(w0, Bv.s, acc0, 0, 0, 0); \
        acc1 = __builtin_amdgcn_mfma_f32_16x16x32_bf16(w1, Bv.s, acc1, 0, 0, 0); \
    }                                                                        \
} while (0)

    // prologue: pair 0 -> tiles buf0 + weights buf0; pair 1 -> regs (svB)
    WLOAD(0);
    WWRITE(0);
    TLOADP(svA, 0);
    TWRITEP(0, svA);
    TLOADP(svB, 1);
    __syncthreads();

    // body for pair p (buf = p&1), unroll-2 so svA/svB alternate with no copies:
    // even p: TLOAD svA (pair p+2), write svB (pair p+1); odd p: vice versa.
    #pragma unroll 2
    for (int p = 0; p < 16; ++p) {
        int buf = p & 1;
        if (p + 2 < 16) {
            if (buf == 0) TLOADP(svA, p + 2); else TLOADP(svB, p + 2);
        }
        if (p + 1 < 16) WLOAD(p + 1);
        COMPT(buf, 0);
        COMPT(buf, 1);
        if (p + 1 < 16) {
            if (buf == 0) TWRITEP(1, svB); else TWRITEP(0, svA);
            WWRITE(buf ^ 1);
            __syncthreads();
        }
    }

#undef TLOADP
#undef TWRITEP
#undef WLOAD
#undef WWRITE
#undef COMPT

    float dp = (dpv[0] + dpv[1]) + (dpv[2] + dpv[3]);
    dp += __shfl_xor(dp, 16, 64);
    dp += __shfl_xor(dp, 32, 64);

    int sp = pz * (DN * DN) + py * DN + px;
    float4v b0 = *(const float4v*)&bias[g * 4];
    float4v b1 = *(const float4v*)&bias[16 + g * 4];
    #pragma unroll
    for (int r = 0; r < 4; ++r) {
        int oc0 = g * 4 + r;
        int oc1 = 16 + g * 4 + r;
        Dout[(size_t)(b * C + oc0) * DVOL + sp] = acc0[r] + b0[r];
        Dout[(size_t)(b * C + oc1) * DVOL + sp] = acc1[r] + b1[r];
    }
    if (g == 0)
        Dsum[b * DVOL + sp] = dp + wsum[2048];
}

// ---- K2: 5^3 gaussian, LDS-staged. Block = (4z x 8y x 8x), 256 blocks.
__global__ __launch_bounds__(256) void k_gauss(const float* __restrict__ Dsum,
                                               const float* __restrict__ gaus_w,
                                               float* __restrict__ filt,
                                               float* __restrict__ outg) {
    __shared__ float tg[8 * 12 * 12];   // 1152
    __shared__ float gk[125];
    int bid = blockIdx.x;
    int xt = bid & 3, yt = (bid >> 2) & 3, zt = (bid >> 4) & 7, b = bid >> 7;
    int tid = threadIdx.x;
    if (tid < 125) gk[tid] = gaus_w[tid];   // replicated kernel: [0][0] slice
    const float* Ds = Dsum + b * DVOL;
    for (int i = tid; i < 1152; i += 256) {
        int lx = i % 12; int r = i / 12; int ly = r % 12; int lz = r / 12;
        int gz = zt * 4 - 2 + lz, gy = yt * 8 - 2 + ly, gx = xt * 8 - 2 + lx;
        float v = 0.f;
        if ((unsigned)gz < DN && (unsigned)gy < DN && (unsigned)gx < DN)
            v = Ds[(gz * DN + gy) * DN + gx];
        tg[i] = v;
    }
    __syncthreads();
    int px = tid & 7, py = (tid >> 3) & 7, pz = tid >> 6;
    const float inv31 = 1.f / 31.f;
    float zb = (float)(zt * 4 + pz - 2);
    float yb = (float)(yt * 8 + py - 2);
    float xb = (float)(xt * 8 + px - 2);
    float p = 0.f, a0 = 0.f, a1 = 0.f, a2 = 0.f;
    for (int tz = 0; tz < 5; ++tz)
    for (int ty = 0; ty < 5; ++ty) {
        int base = ((pz + tz) * 12 + py + ty) * 12 + px;
        #pragma unroll
        for (int tx = 0; tx < 5; ++tx) {
            float g = gk[tz * 25 + ty * 5 + tx];
            float v = g * tg[base + tx];
            p += v;
            a0 = fmaf(v, (zb + (float)tz) * inv31, a0);
            a1 = fmaf(v, (yb + (float)ty) * inv31, a1);
            a2 = fmaf(v, (xb + (float)tx) * inv31, a2);
        }
    }
    float denom = p + 1e-6f;
    float f0 = fminf(fmaxf(a0 / denom * 2.f - 1.f, -1.f), 1.f);
    float f1 = fminf(fmaxf(a1 / denom * 2.f - 1.f, -1.f), 1.f);
    float f2 = fminf(fmaxf(a2 / denom * 2.f - 1.f, -1.f), 1.f);
    int sp = ((zt * 4 + pz) * DN + yt * 8 + py) * DN + xt * 8 + px;
    filt[(b * 3 + 0) * DVOL + sp] = f0;
    filt[(b * 3 + 1) * DVOL + sp] = f1;
    filt[(b * 3 + 2) * DVOL + sp] = f2;
    outg[(size_t)(b * DVOL + sp) * 3 + 0] = f0;
    outg[(size_t)(b * DVOL + sp) * 3 + 1] = f1;
    outg[(size_t)(b * DVOL + sp) * 3 + 2] = f2;
}

// ---- K3: trilinear grid sample. 8192 blocks x 128 thr; tile (2z,4y,16x),
// 2 channels per block -> 64 waves/CU oversubscription (TLP latency hiding).
__global__ __launch_bounds__(128) void k_sample(const float* __restrict__ x,
                                                const float* __restrict__ filt,
                                                float* __restrict__ y) {
    int bid = blockIdx.x;
    int wid = (bid & 7) * 1024 + (bid >> 3);  // 8192%8==0, bijective chunk
    int xt = wid & 1;
    int yt = (wid >> 1) & 7;
    int zt = (wid >> 4) & 15;
    int cgrp = (wid >> 8) & 15;               // 16 groups x 2 channels
    int b  = wid >> 12;
    int tid = threadIdx.x;
    int px = tid & 15, py = (tid >> 4) & 3, pz = tid >> 6;
    int sp = ((zt * 2 + pz) * DN + yt * 4 + py) * DN + xt * 16 + px;
    const float* fb = filt + b * 3 * DVOL;
    float g0 = fb[sp], g1 = fb[DVOL + sp], g2 = fb[2 * DVOL + sp];

    float ix = ((g0 + 1.0f) * (float)XN - 1.0f) * 0.5f;
    float iy = ((g1 + 1.0f) * (float)XN - 1.0f) * 0.5f;
    float iz = ((g2 + 1.0f) * (float)XN - 1.0f) * 0.5f;
    float x0f = floorf(ix), y0f = floorf(iy), z0f = floorf(iz);
    float wx = ix - x0f, wyf = iy - y0f, wz = iz - z0f;
    int x0 = (int)x0f, y0i = (int)y0f, z0 = (int)z0f;

    int offs[8];
    float wts[8];
    #pragma unroll
    for (int t = 0; t < 8; ++t) {
        int dz = t >> 2, dy = (t >> 1) & 1, dx = t & 1;
        int zc = z0 + dz, yc = y0i + dy, xc = x0 + dx;
        bool valid = (unsigned)zc < (unsigned)XN && (unsigned)yc < (unsigned)XN &&
                     (unsigned)xc < (unsigned)XN;
        int zcl = min(max(zc, 0), XN - 1);
        int ycl = min(max(yc, 0), XN - 1);
        int xcl = min(max(xc, 0), XN - 1);
        offs[t] = zcl * (XN * XN) + ycl * XN + xcl;
        float w = (dz ? wz : 1.f - wz) * (dy ? wyf : 1.f - wyf) * (dx ? wx : 1.f - wx);
        wts[t] = valid ? w : 0.f;
    }

    const float* xc0 = x + (size_t)(b * C + cgrp * 2) * XVOL;
    float t0[8], t1[8];
    #pragma unroll
    for (int k = 0; k < 8; ++k) t0[k] = xc0[offs[k]];
    #pragma unroll
    for (int k = 0; k < 8; ++k) t1[k] = xc0[XVOL + offs[k]];

    float a0 = 0.f, a1 = 0.f;
    #pragma unroll
    for (int k = 0; k < 8; ++k) a0 = fmaf(wts[k], t0[k], a0);
    #pragma unroll
    for (int k = 0; k < 8; ++k) a1 = fmaf(wts[k], t1[k], a1);
    y[(size_t)(b * C + cgrp * 2 + 0) * DVOL + sp] = a0;
    y[(size_t)(b * C + cgrp * 2 + 1) * DVOL + sp] = a1;
}

extern "C" void kernel_launch(void* const* d_in, const int* in_sizes, int n_in,
                              void* d_out, int out_size, void* d_ws, size_t ws_size,
                              hipStream_t stream) {
    const float* x      = (const float*)d_in[0];
    const float* conv_w = (const float*)d_in[1];
    const float* conv_b = (const float*)d_in[2];
    const float* gaus_w = (const float*)d_in[3];

    float* out = (float*)d_out;
    float* y_out = out;
    float* D_out = out + (size_t)2097152;
    float* g_out = out + (size_t)4194304;

    float* ws   = (float*)d_ws;
    float* Dsum = ws;                         // 65536 f
    float* filt = ws + 65536;                 // 196608 f
    float* wsum = ws + 262144;                // 2049 f (+pad to 2112)
    unsigned short* wfrag = (unsigned short*)(ws + 264256);  // 65536 u16

    k_prep<<<dim3(512), dim3(256), 0, stream>>>(conv_w, conv_b, wfrag, wsum);
    k_conv_mfma<<<dim3(1024), dim3(256), 0, stream>>>(x, wfrag, wsum, conv_b,
                                                      D_out, Dsum);
    k_gauss<<<dim3(256), dim3(256), 0, stream>>>(Dsum, gaus_w, filt, g_out);
    k_sample<<<dim3(8192), dim3(128), 0, stream>>>(x, filt, y_out);
    (void)in_sizes; (void)n_in; (void)out_size; (void)ws_size;
}

// Round 18
// 84.483 us; speedup vs baseline: 1.1493x; 1.1493x over previous
//
#include <hip/hip_runtime.h>
#include <hip/hip_bf16.h>

// ---------------------------------------------------------------------------
// Def_DownSampling, round 18 = exact revert to R16 (best: 84.5 us).
//  * gaus_w identical per (oc,ic) => gaussian path uses channel-summed field.
//  * conv3+avgpool folded to stride-2 4^3 conv (W4), exact algebra.
//  * D via bf16 MFMA; Dsum kept fp32 (packed dot) for the grid path.
//  * conv: zero-padded fp32 tap tile in LDS (kills shmask VALU bill) +
//    weight LDS double-buffer; 32 light barriers; 4 blocks/CU.
//  * R17's pair-buffering regressed (VGPR 56->116, Occ 35->20%) — reverted.
// Outputs: y (2,32,32,32,32) | D (2,32,32,32,32) | grid-mean (2,32,32,32,3)
// ---------------------------------------------------------------------------

#define XN 64
#define DN 32
#define C  32
#define XVOL (XN * XN * XN)   // 262144
#define DVOL (DN * DN * DN)   // 32768

typedef __attribute__((ext_vector_type(8))) short short8v;
typedef __attribute__((ext_vector_type(4))) float float4v;

struct __attribute__((packed, aligned(4))) f4u { float4v v; };
struct __attribute__((packed, aligned(4))) s8u { short8v v; };

static __device__ __forceinline__ short f2bf(float f) {
    union { float f; unsigned u; } v; v.f = f;
    unsigned r = (v.u + 0x7fffu + ((v.u >> 16) & 1u)) >> 16;   // RNE
    return (short)r;
}

static __device__ __forceinline__ unsigned pk2(float a, float b) {
    __hip_bfloat162 h = __float22bfloat162_rn(float2{a, b});
    union { __hip_bfloat162 h2; unsigned u; } cv; cv.h2 = h;
    return cv.u;
}

// W4[ic][u][oc] = (1/8) sum_{s in {0,1}^3} conv_w[oc][ic][u-s]
static __device__ __forceinline__ float w4val(const float* __restrict__ conv_w,
                                              int ic, int u, int oc) {
    int uz = u >> 4, uy = (u >> 2) & 3, ux = u & 3;
    float s = 0.f;
    #pragma unroll
    for (int sz = 0; sz < 2; ++sz) {
        int tz = uz - sz; if (tz < 0 || tz > 2) continue;
        #pragma unroll
        for (int sy = 0; sy < 2; ++sy) {
            int ty = uy - sy; if (ty < 0 || ty > 2) continue;
            #pragma unroll
            for (int sx = 0; sx < 2; ++sx) {
                int tx = ux - sx; if (tx < 0 || tx > 2) continue;
                s += conv_w[(oc * C + ic) * 27 + tz * 9 + ty * 3 + tx];
            }
        }
    }
    return 0.125f * s;
}

// ---- K0: blocks 0..255 pack A-fragments (bf16) + biassum;
//          blocks 256..511 compute wsum[k] = sum_oc W4[k][oc] via shfl tree.
__global__ __launch_bounds__(256) void k_prep(const float* __restrict__ conv_w,
                                              const float* __restrict__ conv_b,
                                              unsigned short* __restrict__ wfrag,
                                              float* __restrict__ wsum) {
    int bid = blockIdx.x;
    int tid = threadIdx.x;
    if (bid < 256) {
        int i = bid * 256 + tid;                // 65536
        int e = i & 7;
        int l = (i >> 3) & 63;
        int sf = i >> 9;
        int f = sf & 1, step = sf >> 1;
        int oc = f * 16 + (l & 15);
        int k = step * 32 + ((l >> 4) * 8 + e);
        float v = w4val(conv_w, k >> 6, k & 63, oc);
        wfrag[i] = (unsigned short)f2bf(v);
        if (i == 0) {
            float s = 0.f;
            for (int o = 0; o < C; ++o) s += conv_b[o];
            wsum[2048] = s;
        }
    } else {
        int i2 = (bid - 256) * 256 + tid;       // 65536 = 2048 k x 32 oc
        int oc = tid & 31;
        int kk = i2 >> 5;
        float v = w4val(conv_w, kk >> 6, kk & 63, oc);
        v += __shfl_xor(v, 1, 64);
        v += __shfl_xor(v, 2, 64);
        v += __shfl_xor(v, 4, 64);
        v += __shfl_xor(v, 8, 64);
        v += __shfl_xor(v, 16, 64);
        if (oc == 0) wsum[kk] = v;
    }
}

// ---- K1: MFMA conv. 1024 blocks x 256 thr (4 waves).
// Wave w = output (zt*2+(w>>1), yt*2+(w&1), xt*16 + col), all 32 oc.
// Taps: zero-padded fp32 LDS tile 6x6x34 (stride 36), double-buffered per ic.
// Weights: LDS double-buffer, 2 ic (8 KB) per stage (R13/R15 pattern).
#define NSTG (6 * 6 * 34)     // 1224 staged floats per ic
#define TILEF (6 * 6 * 36)    // 1296 with row padding

__global__ __launch_bounds__(256) void k_conv_mfma(
        const float* __restrict__ x, const unsigned short* __restrict__ wfrag,
        const float* __restrict__ wsum, const float* __restrict__ bias,
        float* __restrict__ Dout, float* __restrict__ Dsum) {
    __shared__ float wsl[2112];
    __shared__ char wbuf[2 * 8320];
    __shared__ float tile[2][TILEF];
    int tid = threadIdx.x;
    for (int i = tid; i < 513; i += 256)
        *(float4v*)&wsl[i * 4] = *(const float4v*)&wsum[i * 4];

    int bid = blockIdx.x;
    int wid = (bid & 7) * 128 + (bid >> 3);      // XCD-chunked swizzle (1024%8==0)
    int xt = wid & 1;
    int yt = (wid >> 1) & 15;
    int zt = (wid >> 5) & 15;
    int b  = wid >> 9;
    int w = tid >> 6, lane = tid & 63;
    int col = lane & 15, g = lane >> 4;
    int wpz = w >> 1, wpy = w & 1;
    int pz = zt * 2 + wpz, py = yt * 2 + wpy, px = xt * 16 + col;

    const float* xb = x + (size_t)b * C * XVOL;
    const char* wfb = (const char*)wfrag;
    int wsdst = (tid >> 6) * 1040 + (tid & 63) * 16;

    // hoisted tap-staging index math (ic-invariant): i = tid + it*256 < 1224
    int gz0 = zt * 4 - 1, gy0 = yt * 4 - 1, gx0 = xt * 32 - 1;
    int  soff[5], sdst[5];
    bool sval[5], swr[5];
    #pragma unroll
    for (int it = 0; it < 5; ++it) {
        int i = tid + it * 256;
        int lx = i % 34; int r = i / 34; int ly = r % 6; int lz = r / 6;
        int gz = gz0 + lz, gy = gy0 + ly, gx = gx0 + lx;
        bool inr = i < NSTG;
        swr[it]  = inr;
        sval[it] = inr && (unsigned)gz < XN && (unsigned)gy < XN && (unsigned)gx < XN;
        soff[it] = ((gz & 63) * XN + (gy & 63)) * XN + (gx & 63);
        sdst[it] = inr ? (lz * 6 + ly) * 36 + lx : 0;
    }

    // per-lane LDS read base: z part (2wpz + g>>1), y part 2wpy + (g&1)*2
    int base_g = ((2 * wpz + (g >> 1)) * 6 + 2 * wpy + (g & 1) * 2) * 36 + 2 * col;

    float4v acc0 = {0.f, 0.f, 0.f, 0.f};
    float4v acc1 = {0.f, 0.f, 0.f, 0.f};
    float4v dpv = {0.f, 0.f, 0.f, 0.f};
    float svA[5], svB[5];
    short8v sg0, sg1;

#define TLOAD(SV, j) do {                                                    \
    const float* xp = xb + (size_t)(j) * XVOL;                               \
    _Pragma("unroll")                                                        \
    for (int it = 0; it < 5; ++it)                                           \
        SV[it] = sval[it] ? xp[soff[it]] : 0.f;                              \
} while (0)

#define TWRITE(dst, SV) do {                                                 \
    _Pragma("unroll")                                                        \
    for (int it = 0; it < 5; ++it)                                           \
        if (swr[it]) (dst)[sdst[it]] = SV[it];                               \
} while (0)

#define WLOAD(st) do {                                                       \
    const char* wp = wfb + (size_t)(st) * 8192 + tid * 16;                   \
    sg0 = ((const s8u*)(wp))->v;                                             \
    sg1 = ((const s8u*)(wp + 4096))->v;                                      \
} while (0)

#define WWRITE(bf) do {                                                      \
    *(short8v*)(wbuf + (bf) * 8320 + wsdst) = sg0;                           \
    *(short8v*)(wbuf + (bf) * 8320 + 4160 + wsdst) = sg1;                    \
} while (0)

#define COMPT(ic) do {                                                       \
    const float* t = tile[(ic) & 1];                                         \
    _Pragma("unroll")                                                        \
    for (int h5 = 0; h5 < 2; ++h5) {                                         \
        int off0 = base_g + h5 * 432;                                        \
        float2 v01 = *(const float2*)&t[off0];                               \
        float2 v23 = *(const float2*)&t[off0 + 2];                           \
        float2 v45 = *(const float2*)&t[off0 + 36];                          \
        float2 v67 = *(const float2*)&t[off0 + 38];                          \
        float4v r0 = {v01.x, v01.y, v23.x, v23.y};                           \
        float4v r1 = {v45.x, v45.y, v67.x, v67.y};                           \
        const float4v wlo = *(const float4v*)&wsl[((ic) * 2 + h5) * 32 + g * 8];     \
        const float4v whi = *(const float4v*)&wsl[((ic) * 2 + h5) * 32 + g * 8 + 4]; \
        dpv += wlo * r0;                                                     \
        dpv += whi * r1;                                                     \
        union { short8v s; unsigned u[4]; } Bv;                              \
        Bv.u[0] = pk2(r0[0], r0[1]); Bv.u[1] = pk2(r0[2], r0[3]);            \
        Bv.u[2] = pk2(r1[0], r1[1]); Bv.u[3] = pk2(r1[2], r1[3]);            \
        const char* wl = wbuf + (((ic) >> 1) & 1) * 8320 + ((ic) & 1) * 4160 \
                         + lane * 16;                                        \
        short8v w0 = *(const short8v*)(wl + (h5 * 2) * 1040);                \
        short8v w1 = *(const short8v*)(wl + (h5 * 2 + 1) * 1040);            \
        acc0 = __builtin_amdgcn_mfma_f32_16x16x32_bf16(w0, Bv.s, acc0, 0, 0, 0); \
        acc1 = __builtin_amdgcn_mfma_f32_16x16x32_bf16(w1, Bv.s, acc1, 0, 0, 0); \
    }                                                                        \
} while (0)

    // prologue: weights group 0; taps ic0 staged, ic1 in regs
    WLOAD(0);
    WWRITE(0);
    {
        float sv[5];
        TLOAD(sv, 0);
        TWRITE(tile[0], sv);
    }
    TLOAD(svB, 1);
    __syncthreads();

    for (int st = 0; st < 16; ++st) {
        int ic0 = 2 * st, ic1 = 2 * st + 1;
        // even ic body
        if (st > 0) __syncthreads();
        TWRITE(tile[1], svB);                 // taps for ic1
        if (ic0 + 2 < C) TLOAD(svA, ic0 + 2);
        if (st < 15) WLOAD(st + 1);           // weights group st+1 (issue-early)
        COMPT(ic0);
        // odd ic body
        __syncthreads();
        if (ic0 + 2 < C) TWRITE(tile[0], svA);
        if (ic1 + 2 < C) TLOAD(svB, ic1 + 2);
        COMPT(ic1);
        if (st < 15) WWRITE((st + 1) & 1);    // write-late (2 barriers since readers)
    }

#undef TLOAD
#undef TWRITE
#undef WLOAD
#undef WWRITE
#undef COMPT

    float dp = (dpv[0] + dpv[1]) + (dpv[2] + dpv[3]);
    dp += __shfl_xor(dp, 16, 64);
    dp += __shfl_xor(dp, 32, 64);

    int sp = pz * (DN * DN) + py * DN + px;
    float4v b0 = *(const float4v*)&bias[g * 4];
    float4v b1 = *(const float4v*)&bias[16 + g * 4];
    #pragma unroll
    for (int r = 0; r < 4; ++r) {
        int oc0 = g * 4 + r;
        int oc1 = 16 + g * 4 + r;
        Dout[(size_t)(b * C + oc0) * DVOL + sp] = acc0[r] + b0[r];
        Dout[(size_t)(b * C + oc1) * DVOL + sp] = acc1[r] + b1[r];
    }
    if (g == 0)
        Dsum[b * DVOL + sp] = dp + wsl[2048];
}

// ---- K2: 5^3 gaussian, LDS-staged. Block = (4z x 8y x 8x), 256 blocks.
__global__ __launch_bounds__(256) void k_gauss(const float* __restrict__ Dsum,
                                               const float* __restrict__ gaus_w,
                                               float* __restrict__ filt,
                                               float* __restrict__ outg) {
    __shared__ float tg[8 * 12 * 12];   // 1152
    __shared__ float gk[125];
    int bid = blockIdx.x;
    int xt = bid & 3, yt = (bid >> 2) & 3, zt = (bid >> 4) & 7, b = bid >> 7;
    int tid = threadIdx.x;
    if (tid < 125) gk[tid] = gaus_w[tid];   // replicated kernel: [0][0] slice
    const float* Ds = Dsum + b * DVOL;
    for (int i = tid; i < 1152; i += 256) {
        int lx = i % 12; int r = i / 12; int ly = r % 12; int lz = r / 12;
        int gz = zt * 4 - 2 + lz, gy = yt * 8 - 2 + ly, gx = xt * 8 - 2 + lx;
        float v = 0.f;
        if ((unsigned)gz < DN && (unsigned)gy < DN && (unsigned)gx < DN)
            v = Ds[(gz * DN + gy) * DN + gx];
        tg[i] = v;
    }
    __syncthreads();
    int px = tid & 7, py = (tid >> 3) & 7, pz = tid >> 6;
    const float inv31 = 1.f / 31.f;
    float zb = (float)(zt * 4 + pz - 2);
    float yb = (float)(yt * 8 + py - 2);
    float xb = (float)(xt * 8 + px - 2);
    float p = 0.f, a0 = 0.f, a1 = 0.f, a2 = 0.f;
    for (int tz = 0; tz < 5; ++tz)
    for (int ty = 0; ty < 5; ++ty) {
        int base = ((pz + tz) * 12 + py + ty) * 12 + px;
        #pragma unroll
        for (int tx = 0; tx < 5; ++tx) {
            float g = gk[tz * 25 + ty * 5 + tx];
            float v = g * tg[base + tx];
            p += v;
            a0 = fmaf(v, (zb + (float)tz) * inv31, a0);
            a1 = fmaf(v, (yb + (float)ty) * inv31, a1);
            a2 = fmaf(v, (xb + (float)tx) * inv31, a2);
        }
    }
    float denom = p + 1e-6f;
    float f0 = fminf(fmaxf(a0 / denom * 2.f - 1.f, -1.f), 1.f);
    float f1 = fminf(fmaxf(a1 / denom * 2.f - 1.f, -1.f), 1.f);
    float f2 = fminf(fmaxf(a2 / denom * 2.f - 1.f, -1.f), 1.f);
    int sp = ((zt * 4 + pz) * DN + yt * 8 + py) * DN + xt * 8 + px;
    filt[(b * 3 + 0) * DVOL + sp] = f0;
    filt[(b * 3 + 1) * DVOL + sp] = f1;
    filt[(b * 3 + 2) * DVOL + sp] = f2;
    outg[(size_t)(b * DVOL + sp) * 3 + 0] = f0;
    outg[(size_t)(b * DVOL + sp) * 3 + 1] = f1;
    outg[(size_t)(b * DVOL + sp) * 3 + 2] = f2;
}

// ---- K3: trilinear grid sample. 8192 blocks x 128 thr; tile (2z,4y,16x),
// 2 channels per block -> 64 waves/CU oversubscription (TLP latency hiding).
__global__ __launch_bounds__(128) void k_sample(const float* __restrict__ x,
                                                const float* __restrict__ filt,
                                                float* __restrict__ y) {
    int bid = blockIdx.x;
    int wid = (bid & 7) * 1024 + (bid >> 3);  // 8192%8==0, bijective chunk
    int xt = wid & 1;
    int yt = (wid >> 1) & 7;
    int zt = (wid >> 4) & 15;
    int cgrp = (wid >> 8) & 15;               // 16 groups x 2 channels
    int b  = wid >> 12;
    int tid = threadIdx.x;
    int px = tid & 15, py = (tid >> 4) & 3, pz = tid >> 6;
    int sp = ((zt * 2 + pz) * DN + yt * 4 + py) * DN + xt * 16 + px;
    const float* fb = filt + b * 3 * DVOL;
    float g0 = fb[sp], g1 = fb[DVOL + sp], g2 = fb[2 * DVOL + sp];

    float ix = ((g0 + 1.0f) * (float)XN - 1.0f) * 0.5f;
    float iy = ((g1 + 1.0f) * (float)XN - 1.0f) * 0.5f;
    float iz = ((g2 + 1.0f) * (float)XN - 1.0f) * 0.5f;
    float x0f = floorf(ix), y0f = floorf(iy), z0f = floorf(iz);
    float wx = ix - x0f, wyf = iy - y0f, wz = iz - z0f;
    int x0 = (int)x0f, y0i = (int)y0f, z0 = (int)z0f;

    int offs[8];
    float wts[8];
    #pragma unroll
    for (int t = 0; t < 8; ++t) {
        int dz = t >> 2, dy = (t >> 1) & 1, dx = t & 1;
        int zc = z0 + dz, yc = y0i + dy, xc = x0 + dx;
        bool valid = (unsigned)zc < (unsigned)XN && (unsigned)yc < (unsigned)XN &&
                     (unsigned)xc < (unsigned)XN;
        int zcl = min(max(zc, 0), XN - 1);
        int ycl = min(max(yc, 0), XN - 1);
        int xcl = min(max(xc, 0), XN - 1);
        offs[t] = zcl * (XN * XN) + ycl * XN + xcl;
        float w = (dz ? wz : 1.f - wz) * (dy ? wyf : 1.f - wyf) * (dx ? wx : 1.f - wx);
        wts[t] = valid ? w : 0.f;
    }

    const float* xc0 = x + (size_t)(b * C + cgrp * 2) * XVOL;
    float t0[8], t1[8];
    #pragma unroll
    for (int k = 0; k < 8; ++k) t0[k] = xc0[offs[k]];
    #pragma unroll
    for (int k = 0; k < 8; ++k) t1[k] = xc0[XVOL + offs[k]];

    float a0 = 0.f, a1 = 0.f;
    #pragma unroll
    for (int k = 0; k < 8; ++k) a0 = fmaf(wts[k], t0[k], a0);
    #pragma unroll
    for (int k = 0; k < 8; ++k) a1 = fmaf(wts[k], t1[k], a1);
    y[(size_t)(b * C + cgrp * 2 + 0) * DVOL + sp] = a0;
    y[(size_t)(b * C + cgrp * 2 + 1) * DVOL + sp] = a1;
}

extern "C" void kernel_launch(void* const* d_in, const int* in_sizes, int n_in,
                              void* d_out, int out_size, void* d_ws, size_t ws_size,
                              hipStream_t stream) {
    const float* x      = (const float*)d_in[0];
    const float* conv_w = (const float*)d_in[1];
    const float* conv_b = (const float*)d_in[2];
    const float* gaus_w = (const float*)d_in[3];

    float* out = (float*)d_out;
    float* y_out = out;
    float* D_out = out + (size_t)2097152;
    float* g_out = out + (size_t)4194304;

    float* ws   = (float*)d_ws;
    float* Dsum = ws;                         // 65536 f
    float* filt = ws + 65536;                 // 196608 f
    float* wsum = ws + 262144;                // 2049 f (+pad to 2112)
    unsigned short* wfrag = (unsigned short*)(ws + 264256);  // 65536 u16

    k_prep<<<dim3(512), dim3(256), 0, stream>>>(conv_w, conv_b, wfrag, wsum);
    k_conv_mfma<<<dim3(1024), dim3(256), 0, stream>>>(x, wfrag, wsum, conv_b,
                                                      D_out, Dsum);
    k_gauss<<<dim3(256), dim3(256), 0, stream>>>(Dsum, gaus_w, filt, g_out);
    k_sample<<<dim3(8192), dim3(128), 0, stream>>>(x, filt, y_out);
    (void)in_sizes; (void)n_in; (void)out_size; (void)ws_size;
}

// Round 19
// 84.455 us; speedup vs baseline: 1.1497x; 1.0003x over previous
//
#include <hip/hip_runtime.h>
#include <hip/hip_bf16.h>

// ---------------------------------------------------------------------------
// Def_DownSampling, round 19.
//  * gaus_w identical per (oc,ic) => gaussian path uses channel-summed field.
//  * conv3+avgpool folded to stride-2 4^3 conv (W4), exact algebra.
//  * D via bf16 MFMA; Dsum kept fp32 (packed dot) for the grid path.
//  * R19: 16 barriers (pair-granular dbuf) with R16's register budget:
//    SINGLE svT register set — consume (TWRITEP) right after the barrier
//    whose implicit vmcnt(0) drain is then free (loads issued 2 COMPTs ago),
//    reissue into the same regs. wsl -> per-pair wsb (LDS 38.4 KB, 4 blk/CU).
//    R17's regression causes (2 reg sets -> VGPR 116) avoided.
// Outputs: y (2,32,32,32,32) | D (2,32,32,32,32) | grid-mean (2,32,32,32,3)
// ---------------------------------------------------------------------------

#define XN 64
#define DN 32
#define C  32
#define XVOL (XN * XN * XN)   // 262144
#define DVOL (DN * DN * DN)   // 32768

typedef __attribute__((ext_vector_type(8))) short short8v;
typedef __attribute__((ext_vector_type(4))) float float4v;

struct __attribute__((packed, aligned(4))) f4u { float4v v; };
struct __attribute__((packed, aligned(4))) s8u { short8v v; };

static __device__ __forceinline__ short f2bf(float f) {
    union { float f; unsigned u; } v; v.f = f;
    unsigned r = (v.u + 0x7fffu + ((v.u >> 16) & 1u)) >> 16;   // RNE
    return (short)r;
}

static __device__ __forceinline__ unsigned pk2(float a, float b) {
    __hip_bfloat162 h = __float22bfloat162_rn(float2{a, b});
    union { __hip_bfloat162 h2; unsigned u; } cv; cv.h2 = h;
    return cv.u;
}

// W4[ic][u][oc] = (1/8) sum_{s in {0,1}^3} conv_w[oc][ic][u-s]
static __device__ __forceinline__ float w4val(const float* __restrict__ conv_w,
                                              int ic, int u, int oc) {
    int uz = u >> 4, uy = (u >> 2) & 3, ux = u & 3;
    float s = 0.f;
    #pragma unroll
    for (int sz = 0; sz < 2; ++sz) {
        int tz = uz - sz; if (tz < 0 || tz > 2) continue;
        #pragma unroll
        for (int sy = 0; sy < 2; ++sy) {
            int ty = uy - sy; if (ty < 0 || ty > 2) continue;
            #pragma unroll
            for (int sx = 0; sx < 2; ++sx) {
                int tx = ux - sx; if (tx < 0 || tx > 2) continue;
                s += conv_w[(oc * C + ic) * 27 + tz * 9 + ty * 3 + tx];
            }
        }
    }
    return 0.125f * s;
}

// ---- K0: blocks 0..255 pack A-fragments (bf16) + biassum;
//          blocks 256..511 compute wsum[k] = sum_oc W4[k][oc] via shfl tree.
__global__ __launch_bounds__(256) void k_prep(const float* __restrict__ conv_w,
                                              const float* __restrict__ conv_b,
                                              unsigned short* __restrict__ wfrag,
                                              float* __restrict__ wsum) {
    int bid = blockIdx.x;
    int tid = threadIdx.x;
    if (bid < 256) {
        int i = bid * 256 + tid;                // 65536
        int e = i & 7;
        int l = (i >> 3) & 63;
        int sf = i >> 9;
        int f = sf & 1, step = sf >> 1;
        int oc = f * 16 + (l & 15);
        int k = step * 32 + ((l >> 4) * 8 + e);
        float v = w4val(conv_w, k >> 6, k & 63, oc);
        wfrag[i] = (unsigned short)f2bf(v);
        if (i == 0) {
            float s = 0.f;
            for (int o = 0; o < C; ++o) s += conv_b[o];
            wsum[2048] = s;
        }
    } else {
        int i2 = (bid - 256) * 256 + tid;       // 65536 = 2048 k x 32 oc
        int oc = tid & 31;
        int kk = i2 >> 5;
        float v = w4val(conv_w, kk >> 6, kk & 63, oc);
        v += __shfl_xor(v, 1, 64);
        v += __shfl_xor(v, 2, 64);
        v += __shfl_xor(v, 4, 64);
        v += __shfl_xor(v, 8, 64);
        v += __shfl_xor(v, 16, 64);
        if (oc == 0) wsum[kk] = v;
    }
}

// ---- K1: MFMA conv. 1024 blocks x 256 thr (4 waves).
// Wave w = output (zt*2+(w>>1), yt*2+(w&1), xt*16 + col), all 32 oc.
// Pair-granular double buffers (taps tile[2][2xTILEF], weights wbuf[2],
// wsum slice wsb[2]); ONE register set svT/sg; 16 barriers, each with
// ~2-COMPT load cover so the implicit vmcnt(0) drain is cheap.
#define NSTG (6 * 6 * 34)     // 1224 staged floats per ic
#define TILEF (6 * 6 * 36)    // 1296 with row padding

__global__ __launch_bounds__(256) void k_conv_mfma(
        const float* __restrict__ x, const unsigned short* __restrict__ wfrag,
        const float* __restrict__ wsum, const float* __restrict__ bias,
        float* __restrict__ Dout, float* __restrict__ Dsum) {
    __shared__ float tile[2][2 * TILEF];
    __shared__ char wbuf[2 * 8320];
    __shared__ float wsb[2][132];
    int tid = threadIdx.x;

    int bid = blockIdx.x;
    int wid = (bid & 7) * 128 + (bid >> 3);      // XCD-chunked swizzle (1024%8==0)
    int xt = wid & 1;
    int yt = (wid >> 1) & 15;
    int zt = (wid >> 5) & 15;
    int b  = wid >> 9;
    int w = tid >> 6, lane = tid & 63;
    int col = lane & 15, g = lane >> 4;
    int wpz = w >> 1, wpy = w & 1;
    int pz = zt * 2 + wpz, py = yt * 2 + wpy, px = xt * 16 + col;

    const float* xb = x + (size_t)b * C * XVOL;
    const char* wfb = (const char*)wfrag;
    int wsdst = (tid >> 6) * 1040 + (tid & 63) * 16;

    // hoisted tap-staging index math (ic-invariant): i = tid + it*256 < 1224
    int gz0 = zt * 4 - 1, gy0 = yt * 4 - 1, gx0 = xt * 32 - 1;
    int  soff[5], sdst[5];
    bool sval[5], swr[5];
    #pragma unroll
    for (int it = 0; it < 5; ++it) {
        int i = tid + it * 256;
        int lx = i % 34; int r = i / 34; int ly = r % 6; int lz = r / 6;
        int gz = gz0 + lz, gy = gy0 + ly, gx = gx0 + lx;
        bool inr = i < NSTG;
        swr[it]  = inr;
        sval[it] = inr && (unsigned)gz < XN && (unsigned)gy < XN && (unsigned)gx < XN;
        soff[it] = ((gz & 63) * XN + (gy & 63)) * XN + (gx & 63);
        sdst[it] = inr ? (lz * 6 + ly) * 36 + lx : 0;
    }

    int base_g = ((2 * wpz + (g >> 1)) * 6 + 2 * wpy + (g & 1) * 2) * 36 + 2 * col;

    float4v acc0 = {0.f, 0.f, 0.f, 0.f};
    float4v acc1 = {0.f, 0.f, 0.f, 0.f};
    float4v dpv = {0.f, 0.f, 0.f, 0.f};
    float svT[10];
    short8v sg0, sg1;
    float wv;

// load both ics of pair p into SV[10]
#define TLOADP(SV, p) do {                                                   \
    const float* xp0 = xb + (size_t)(2 * (p)) * XVOL;                        \
    _Pragma("unroll")                                                        \
    for (int it = 0; it < 5; ++it)                                           \
        SV[it] = sval[it] ? xp0[soff[it]] : 0.f;                             \
    const float* xp1 = xp0 + XVOL;                                           \
    _Pragma("unroll")                                                        \
    for (int it = 0; it < 5; ++it)                                           \
        SV[5 + it] = sval[it] ? xp1[soff[it]] : 0.f;                         \
} while (0)

#define TWRITEP(bf, SV) do {                                                 \
    float* d0 = tile[bf];                                                    \
    _Pragma("unroll")                                                        \
    for (int it = 0; it < 5; ++it)                                           \
        if (swr[it]) d0[sdst[it]] = SV[it];                                  \
    float* d1 = tile[bf] + TILEF;                                            \
    _Pragma("unroll")                                                        \
    for (int it = 0; it < 5; ++it)                                           \
        if (swr[it]) d1[sdst[it]] = SV[5 + it];                              \
} while (0)

#define WLOAD(p) do {                                                        \
    const char* wp = wfb + (size_t)(p) * 8192 + tid * 16;                    \
    sg0 = ((const s8u*)(wp))->v;                                             \
    sg1 = ((const s8u*)(wp + 4096))->v;                                      \
    wv = (tid < 128) ? wsum[(p) * 128 + tid] : 0.f;                          \
} while (0)

#define WWRITE(bf) do {                                                      \
    *(short8v*)(wbuf + (bf) * 8320 + wsdst) = sg0;                           \
    *(short8v*)(wbuf + (bf) * 8320 + 4160 + wsdst) = sg1;                    \
    if (tid < 128) wsb[bf][tid] = wv;                                        \
} while (0)

// compute one ic; icL selects half of the pair buffers
#define COMPT(bf, icL) do {                                                  \
    const float* t = tile[bf] + (icL) * TILEF;                               \
    _Pragma("unroll")                                                        \
    for (int h5 = 0; h5 < 2; ++h5) {                                         \
        int off0 = base_g + h5 * 432;                                        \
        float2 v01 = *(const float2*)&t[off0];                               \
        float2 v23 = *(const float2*)&t[off0 + 2];                           \
        float2 v45 = *(const float2*)&t[off0 + 36];                          \
        float2 v67 = *(const float2*)&t[off0 + 38];                          \
        float4v r0 = {v01.x, v01.y, v23.x, v23.y};                           \
        float4v r1 = {v45.x, v45.y, v67.x, v67.y};                           \
        const float4v wlo = *(const float4v*)&wsb[bf][((icL) * 2 + h5) * 32 + g * 8];     \
        const float4v whi = *(const float4v*)&wsb[bf][((icL) * 2 + h5) * 32 + g * 8 + 4]; \
        dpv += wlo * r0;                                                     \
        dpv += whi * r1;                                                     \
        union { short8v s; unsigned u[4]; } Bv;                              \
        Bv.u[0] = pk2(r0[0], r0[1]); Bv.u[1] = pk2(r0[2], r0[3]);            \
        Bv.u[2] = pk2(r1[0], r1[1]); Bv.u[3] = pk2(r1[2], r1[3]);            \
        const char* wl = wbuf + (bf) * 8320 + (icL) * 4160 + lane * 16;      \
        short8v w0 = *(const short8v*)(wl + (h5 * 2) * 1040);                \
        short8v w1 = *(const short8v*)(wl + (h5 * 2 + 1) * 1040);            \
        acc0 = __builtin_amdgcn_mfma_f32_16x16x32_bf16(w0, Bv.s, acc0, 0, 0, 0); \
        acc1 = __builtin_amdgcn_mfma_f32_16x16x32_bf16(w1, Bv.s, acc1, 0, 0, 0); \
    }                                                                        \
} while (0)

    // prologue: pair 0 -> LDS buf 0; pair 1 -> registers (svT, sg, wv)
    WLOAD(0);
    WWRITE(0);
    TLOADP(svT, 0);
    TWRITEP(0, svT);
    TLOADP(svT, 1);
    WLOAD(1);
    __syncthreads();

    for (int p = 0; p < 16; ++p) {
        if (p > 0) __syncthreads();          // drain = pair p+1 loads, issued
                                             // 2 COMPTs ago -> cheap
        if (p + 1 < 16) {
            TWRITEP((p + 1) & 1, svT);       // consume registers
            WWRITE((p + 1) & 1);
        }
        if (p + 2 < 16) {                    // reissue into the same registers
            TLOADP(svT, p + 2);
            WLOAD(p + 2);
        }
        COMPT(p & 1, 0);
        COMPT(p & 1, 1);
    }

#undef TLOADP
#undef TWRITEP
#undef WLOAD
#undef WWRITE
#undef COMPT

    float dp = (dpv[0] + dpv[1]) + (dpv[2] + dpv[3]);
    dp += __shfl_xor(dp, 16, 64);
    dp += __shfl_xor(dp, 32, 64);

    int sp = pz * (DN * DN) + py * DN + px;
    float4v b0 = *(const float4v*)&bias[g * 4];
    float4v b1 = *(const float4v*)&bias[16 + g * 4];
    #pragma unroll
    for (int r = 0; r < 4; ++r) {
        int oc0 = g * 4 + r;
        int oc1 = 16 + g * 4 + r;
        Dout[(size_t)(b * C + oc0) * DVOL + sp] = acc0[r] + b0[r];
        Dout[(size_t)(b * C + oc1) * DVOL + sp] = acc1[r] + b1[r];
    }
    if (g == 0)
        Dsum[b * DVOL + sp] = dp + wsum[2048];
}

// ---- K2: 5^3 gaussian, LDS-staged. Block = (4z x 8y x 8x), 256 blocks.
__global__ __launch_bounds__(256) void k_gauss(const float* __restrict__ Dsum,
                                               const float* __restrict__ gaus_w,
                                               float* __restrict__ filt,
                                               float* __restrict__ outg) {
    __shared__ float tg[8 * 12 * 12];   // 1152
    __shared__ float gk[125];
    int bid = blockIdx.x;
    int xt = bid & 3, yt = (bid >> 2) & 3, zt = (bid >> 4) & 7, b = bid >> 7;
    int tid = threadIdx.x;
    if (tid < 125) gk[tid] = gaus_w[tid];   // replicated kernel: [0][0] slice
    const float* Ds = Dsum + b * DVOL;
    for (int i = tid; i < 1152; i += 256) {
        int lx = i % 12; int r = i / 12; int ly = r % 12; int lz = r / 12;
        int gz = zt * 4 - 2 + lz, gy = yt * 8 - 2 + ly, gx = xt * 8 - 2 + lx;
        float v = 0.f;
        if ((unsigned)gz < DN && (unsigned)gy < DN && (unsigned)gx < DN)
            v = Ds[(gz * DN + gy) * DN + gx];
        tg[i] = v;
    }
    __syncthreads();
    int px = tid & 7, py = (tid >> 3) & 7, pz = tid >> 6;
    const float inv31 = 1.f / 31.f;
    float zb = (float)(zt * 4 + pz - 2);
    float yb = (float)(yt * 8 + py - 2);
    float xb = (float)(xt * 8 + px - 2);
    float p = 0.f, a0 = 0.f, a1 = 0.f, a2 = 0.f;
    for (int tz = 0; tz < 5; ++tz)
    for (int ty = 0; ty < 5; ++ty) {
        int base = ((pz + tz) * 12 + py + ty) * 12 + px;
        #pragma unroll
        for (int tx = 0; tx < 5; ++tx) {
            float g = gk[tz * 25 + ty * 5 + tx];
            float v = g * tg[base + tx];
            p += v;
            a0 = fmaf(v, (zb + (float)tz) * inv31, a0);
            a1 = fmaf(v, (yb + (float)ty) * inv31, a1);
            a2 = fmaf(v, (xb + (float)tx) * inv31, a2);
        }
    }
    float denom = p + 1e-6f;
    float f0 = fminf(fmaxf(a0 / denom * 2.f - 1.f, -1.f), 1.f);
    float f1 = fminf(fmaxf(a1 / denom * 2.f - 1.f, -1.f), 1.f);
    float f2 = fminf(fmaxf(a2 / denom * 2.f - 1.f, -1.f), 1.f);
    int sp = ((zt * 4 + pz) * DN + yt * 8 + py) * DN + xt * 8 + px;
    filt[(b * 3 + 0) * DVOL + sp] = f0;
    filt[(b * 3 + 1) * DVOL + sp] = f1;
    filt[(b * 3 + 2) * DVOL + sp] = f2;
    outg[(size_t)(b * DVOL + sp) * 3 + 0] = f0;
    outg[(size_t)(b * DVOL + sp) * 3 + 1] = f1;
    outg[(size_t)(b * DVOL + sp) * 3 + 2] = f2;
}

// ---- K3: trilinear grid sample. 8192 blocks x 128 thr; tile (2z,4y,16x),
// 2 channels per block -> 64 waves/CU oversubscription (TLP latency hiding).
__global__ __launch_bounds__(128) void k_sample(const float* __restrict__ x,
                                                const float* __restrict__ filt,
                                                float* __restrict__ y) {
    int bid = blockIdx.x;
    int wid = (bid & 7) * 1024 + (bid >> 3);  // 8192%8==0, bijective chunk
    int xt = wid & 1;
    int yt = (wid >> 1) & 7;
    int zt = (wid >> 4) & 15;
    int cgrp = (wid >> 8) & 15;               // 16 groups x 2 channels
    int b  = wid >> 12;
    int tid = threadIdx.x;
    int px = tid & 15, py = (tid >> 4) & 3, pz = tid >> 6;
    int sp = ((zt * 2 + pz) * DN + yt * 4 + py) * DN + xt * 16 + px;
    const float* fb = filt + b * 3 * DVOL;
    float g0 = fb[sp], g1 = fb[DVOL + sp], g2 = fb[2 * DVOL + sp];

    float ix = ((g0 + 1.0f) * (float)XN - 1.0f) * 0.5f;
    float iy = ((g1 + 1.0f) * (float)XN - 1.0f) * 0.5f;
    float iz = ((g2 + 1.0f) * (float)XN - 1.0f) * 0.5f;
    float x0f = floorf(ix), y0f = floorf(iy), z0f = floorf(iz);
    float wx = ix - x0f, wyf = iy - y0f, wz = iz - z0f;
    int x0 = (int)x0f, y0i = (int)y0f, z0 = (int)z0f;

    int offs[8];
    float wts[8];
    #pragma unroll
    for (int t = 0; t < 8; ++t) {
        int dz = t >> 2, dy = (t >> 1) & 1, dx = t & 1;
        int zc = z0 + dz, yc = y0i + dy, xc = x0 + dx;
        bool valid = (unsigned)zc < (unsigned)XN && (unsigned)yc < (unsigned)XN &&
                     (unsigned)xc < (unsigned)XN;
        int zcl = min(max(zc, 0), XN - 1);
        int ycl = min(max(yc, 0), XN - 1);
        int xcl = min(max(xc, 0), XN - 1);
        offs[t] = zcl * (XN * XN) + ycl * XN + xcl;
        float w = (dz ? wz : 1.f - wz) * (dy ? wyf : 1.f - wyf) * (dx ? wx : 1.f - wx);
        wts[t] = valid ? w : 0.f;
    }

    const float* xc0 = x + (size_t)(b * C + cgrp * 2) * XVOL;
    float t0[8], t1[8];
    #pragma unroll
    for (int k = 0; k < 8; ++k) t0[k] = xc0[offs[k]];
    #pragma unroll
    for (int k = 0; k < 8; ++k) t1[k] = xc0[XVOL + offs[k]];

    float a0 = 0.f, a1 = 0.f;
    #pragma unroll
    for (int k = 0; k < 8; ++k) a0 = fmaf(wts[k], t0[k], a0);
    #pragma unroll
    for (int k = 0; k < 8; ++k) a1 = fmaf(wts[k], t1[k], a1);
    y[(size_t)(b * C + cgrp * 2 + 0) * DVOL + sp] = a0;
    y[(size_t)(b * C + cgrp * 2 + 1) * DVOL + sp] = a1;
}

extern "C" void kernel_launch(void* const* d_in, const int* in_sizes, int n_in,
                              void* d_out, int out_size, void* d_ws, size_t ws_size,
                              hipStream_t stream) {
    const float* x      = (const float*)d_in[0];
    const float* conv_w = (const float*)d_in[1];
    const float* conv_b = (const float*)d_in[2];
    const float* gaus_w = (const float*)d_in[3];

    float* out = (float*)d_out;
    float* y_out = out;
    float* D_out = out + (size_t)2097152;
    float* g_out = out + (size_t)4194304;

    float* ws   = (float*)d_ws;
    float* Dsum = ws;                         // 65536 f
    float* filt = ws + 65536;                 // 196608 f
    float* wsum = ws + 262144;                // 2049 f (+pad to 2112)
    unsigned short* wfrag = (unsigned short*)(ws + 264256);  // 65536 u16

    k_prep<<<dim3(512), dim3(256), 0, stream>>>(conv_w, conv_b, wfrag, wsum);
    k_conv_mfma<<<dim3(1024), dim3(256), 0, stream>>>(x, wfrag, wsum, conv_b,
                                                      D_out, Dsum);
    k_gauss<<<dim3(256), dim3(256), 0, stream>>>(Dsum, gaus_w, filt, g_out);
    k_sample<<<dim3(8192), dim3(128), 0, stream>>>(x, filt, y_out);
    (void)in_sizes; (void)n_in; (void)out_size; (void)ws_size;
}